// Round 6
// baseline (1381.604 us; speedup 1.0000x reference)
//
#include <hip/hip_runtime.h>
#include <math.h>

#define N_TOK 65536
#define HID   256
#define FFDIM 1024
#define QKVM  768
#define EPS_LN 1e-5f
#define RBLOCKS 256

typedef __bf16 bf16x8 __attribute__((ext_vector_type(8)));
typedef float  f32x4  __attribute__((ext_vector_type(4)));
typedef unsigned short u16x8 __attribute__((ext_vector_type(8)));

__device__ __forceinline__ float gelu_f(float x) {
    return 0.5f * x * (1.0f + erff(x * 0.70710678118654752f));
}
__device__ __forceinline__ float bf2f(unsigned short u) {
    return __uint_as_float(((unsigned int)u) << 16);
}
__device__ __forceinline__ unsigned short f2bf(float f) {
    unsigned int x = __float_as_uint(f);
    unsigned int r = ((x >> 16) & 1u) + 0x7fffu;
    return (unsigned short)((x + r) >> 16);
}
__device__ __forceinline__ void gload16(const void* g, void* l) {
    __builtin_amdgcn_global_load_lds(
        (const __attribute__((address_space(1))) void*)g,
        (__attribute__((address_space(3))) void*)l, 16, 0, 0);
}

// ------- weight fp32 [L,K,M] -> bf16 transposed [L][moff+M][K], row-scaled by g
__global__ __launch_bounds__(256) void wconv(
    const float* __restrict__ src, const float* __restrict__ g,
    unsigned short* __restrict__ dst,
    const int K, const int M, const size_t dstLS, const int moff)
{
    const int l = blockIdx.z;
    __shared__ float t[32][33];
    const int r  = threadIdx.x >> 3;
    const int c0 = (threadIdx.x & 7) * 4;
    const int bk = blockIdx.x * 32;
    const int bm = blockIdx.y * 32;
    float4 v4 = *(const float4*)(src + (size_t)l * K * M + (size_t)(bk + r) * M + bm + c0);
    if (g) {
        const float gv = g[(size_t)l * K + bk + r];
        v4.x *= gv; v4.y *= gv; v4.z *= gv; v4.w *= gv;
    }
    t[r][c0] = v4.x; t[r][c0+1] = v4.y; t[r][c0+2] = v4.z; t[r][c0+3] = v4.w;
    __syncthreads();
    ushort4 o;
    o.x = f2bf(t[c0+0][r]);
    o.y = f2bf(t[c0+1][r]);
    o.z = f2bf(t[c0+2][r]);
    o.w = f2bf(t[c0+3][r]);
    *(ushort4*)(dst + (size_t)l * dstLS + (size_t)(moff + bm + r) * K + bk + c0) = o;
}

// ------- bias fold: outb[l][moff+m] = bias[l][m] + sum_k bvec[l][k]*W[l][k][m]
__global__ __launch_bounds__(256) void biasfold(
    const float* __restrict__ W, const float* __restrict__ bias,
    const float* __restrict__ bvec, float* __restrict__ outb,
    const int K, const int M, const size_t outLS, const int moff)
{
    const int l = blockIdx.y;
    const int m = blockIdx.x * 256 + threadIdx.x;
    float acc = bias[(size_t)l * M + m];
    const float* Wl = W + (size_t)l * K * M;
    const float* bv = bvec + (size_t)l * K;
    for (int k = 0; k < K; ++k) acc = fmaf(bv[k], Wl[(size_t)k * M + m], acc);
    outb[(size_t)l * outLS + moff + m] = acc;
}

// ------- plain row-normalize (affine folded into weights) -> bf16 -------------
__global__ __launch_bounds__(256) void ln_norm(
    const float* __restrict__ h, unsigned short* __restrict__ nb)
{
    const int row  = blockIdx.x * 4 + (threadIdx.x >> 6);
    const int lane = threadIdx.x & 63;
    const size_t base = (size_t)row * HID + lane * 4;
    const float4 xv = *(const float4*)(h + base);
    float s  = xv.x + xv.y + xv.z + xv.w;
    float s2 = fmaf(xv.x, xv.x, fmaf(xv.y, xv.y, fmaf(xv.z, xv.z, xv.w * xv.w)));
    #pragma unroll
    for (int off = 32; off > 0; off >>= 1) {
        s  += __shfl_xor(s, off, 64);
        s2 += __shfl_xor(s2, off, 64);
    }
    const float m   = s * (1.0f / HID);
    const float var = fmaxf(s2 * (1.0f / HID) - m * m, 0.f);
    const float rs  = rsqrtf(var + EPS_LN);
    ushort4 o;
    o.x = f2bf((xv.x - m) * rs);
    o.y = f2bf((xv.y - m) * rs);
    o.z = f2bf((xv.z - m) * rs);
    o.w = f2bf((xv.w - m) * rs);
    *(ushort4*)(nb + base) = o;
}

// ------- bf16 MFMA GEMM: C = A[N,K](lda) @ Wt[M,K]^T + bias (+res)(+gelu) -----
// 128x128 tile, BK=32, double-buffered 32KB LDS, global_load_lds staging,
// XOR swizzle chunk^(row&3): all 64 lanes of a ds_read_b128 hit distinct 16B.
template<int K, bool GELU_EP, bool RES, bool CBF16>
__global__ __launch_bounds__(256, 4) void mfma_gemm(
    const unsigned short* __restrict__ A, const int lda,
    const unsigned short* __restrict__ Wt,
    const float* __restrict__ bias,
    const float* __restrict__ res,
    void* __restrict__ C, const int M)
{
    constexpr int KT = K / 32;
    __shared__ __align__(16) unsigned short Abuf[2][128 * 32];   // 8KB each
    __shared__ __align__(16) unsigned short Bbuf[2][128 * 32];
    const int tid  = threadIdx.x;
    const int lane = tid & 63;
    const int wv   = tid >> 6;
    const int bn = blockIdx.x * 128;   // col block (fast dim -> A-panel L2 reuse)
    const int bm = blockIdx.y * 128;
    // staging: wave wv covers rows [wv*32, wv*32+32), 2 instrs x 16 rows each.
    const int sr0  = (wv << 5) + (lane >> 2);
    const int schk = (lane & 3) ^ ((lane >> 2) & 3);    // inverse-swizzled source
    const char* Asrc = (const char*)A  + ((size_t)(bm + sr0) * lda + schk * 8) * 2;
    const char* Bsrc = (const char*)Wt + ((size_t)(bn + sr0) * K   + schk * 8) * 2;

    const int lrow = lane & 15;
    const int kgrp = lane >> 4;
    const int wr = (wv >> 1) << 6;
    const int wc = (wv & 1) << 6;

    f32x4 acc[4][4];
    #pragma unroll
    for (int i = 0; i < 4; ++i)
        #pragma unroll
        for (int j = 0; j < 4; ++j)
            acc[i][j] = (f32x4){0.f, 0.f, 0.f, 0.f};

    auto STAGE = [&](int b, int kt) {
        const size_t koff = (size_t)kt * 64;            // 32 bf16 = 64B
        char* ad = (char*)&Abuf[b][0] + (wv << 11);
        char* bd = (char*)&Bbuf[b][0] + (wv << 11);
        #pragma unroll
        for (int i = 0; i < 2; ++i) {
            gload16(Asrc + (size_t)(i * 16) * (lda * 2) + koff, ad + (i << 10));
            gload16(Bsrc + (size_t)(i * 16) * (K * 2)   + koff, bd + (i << 10));
        }
    };

    STAGE(0, 0);
    __syncthreads();
    const int pa = (kgrp ^ (lrow & 3)) << 4;            // swizzled read chunk
    for (int kt = 0; kt < KT; ++kt) {
        const int cur = kt & 1;
        if (kt + 1 < KT) STAGE(cur ^ 1, kt + 1);
        const char* Ab = (const char*)&Abuf[cur][0];
        const char* Bb = (const char*)&Bbuf[cur][0];
        bf16x8 af[4], bfr[4];
        #pragma unroll
        for (int mi = 0; mi < 4; ++mi)
            af[mi] = *(const bf16x8*)(Ab + (wr + mi * 16 + lrow) * 64 + pa);
        #pragma unroll
        for (int ni = 0; ni < 4; ++ni)
            bfr[ni] = *(const bf16x8*)(Bb + (wc + ni * 16 + lrow) * 64 + pa);
        #pragma unroll
        for (int mi = 0; mi < 4; ++mi)
            #pragma unroll
            for (int ni = 0; ni < 4; ++ni)
                acc[mi][ni] = __builtin_amdgcn_mfma_f32_16x16x32_bf16(
                    af[mi], bfr[ni], acc[mi][ni], 0, 0, 0);
        __syncthreads();
    }
    // epilogue: D[row=(lane>>4)*4+r][col=lane&15] per 16x16 fragment
    #pragma unroll
    for (int mi = 0; mi < 4; ++mi) {
        #pragma unroll
        for (int ni = 0; ni < 4; ++ni) {
            const int col = bn + wc + ni * 16 + lrow;
            const float bv = bias[col];
            #pragma unroll
            for (int r = 0; r < 4; ++r) {
                const int row = bm + wr + mi * 16 + kgrp * 4 + r;
                float v = acc[mi][ni][r] + bv;
                if (RES)     v += res[(size_t)row * M + col];
                if (GELU_EP) v  = gelu_f(v);
                if (CBF16) ((unsigned short*)C)[(size_t)row * M + col] = f2bf(v);
                else       ((float*)C)[(size_t)row * M + col] = v;
            }
        }
    }
}

// ------- stage-1 reduction over packed qkv [N][768] ---------------------------
__global__ __launch_bounds__(256) void reduce_kernel(
    const unsigned short* __restrict__ qkv,
    float* __restrict__ pkv, float* __restrict__ pks,
    float* __restrict__ psq, float* __restrict__ psk)
{
    const int b   = blockIdx.x;
    const int tid = threadIdx.x;
    const int cg  = tid & 31;
    const int ro  = tid >> 5;
    const int c   = cg * 8;
    const int r0  = b * (N_TOK / RBLOCKS);
    float kv[8] = {}, ks[8] = {};
    float sq = 0.f, sk = 0.f;
    #pragma unroll 4
    for (int i = 0; i < (N_TOK / RBLOCKS) / 8; ++i) {
        const size_t base = (size_t)(r0 + ro + i * 8) * QKVM;
        const u16x8 q8 = *(const u16x8*)(qkv + base + c);
        const u16x8 k8 = *(const u16x8*)(qkv + base + 256 + c);
        const u16x8 v8 = *(const u16x8*)(qkv + base + 512 + c);
        #pragma unroll
        for (int j = 0; j < 8; ++j) {
            const float qf = bf2f(q8[j]), kf = bf2f(k8[j]), vf = bf2f(v8[j]);
            kv[j] = fmaf(kf, vf, kv[j]);
            ks[j] += kf;
            sq = fmaf(qf, qf, sq);
            sk = fmaf(kf, kf, sk);
        }
    }
    __shared__ float lkv[8][256];
    __shared__ float lks[8][256];
    #pragma unroll
    for (int j = 0; j < 8; ++j) { lkv[ro][c + j] = kv[j]; lks[ro][c + j] = ks[j]; }
    __syncthreads();
    float skv = 0.f, sks = 0.f;
    #pragma unroll
    for (int r = 0; r < 8; ++r) { skv += lkv[r][tid]; sks += lks[r][tid]; }
    pkv[(size_t)b * HID + tid] = skv;
    pks[(size_t)b * HID + tid] = sks;
    #pragma unroll
    for (int off = 32; off > 0; off >>= 1) {
        sq += __shfl_down(sq, off, 64);
        sk += __shfl_down(sk, off, 64);
    }
    __shared__ float s1[4], s2[4];
    if ((tid & 63) == 0) { s1[tid >> 6] = sq; s2[tid >> 6] = sk; }
    __syncthreads();
    if (tid == 0) {
        psq[b] = s1[0] + s1[1] + s1[2] + s1[3];
        psk[b] = s2[0] + s2[1] + s2[2] + s2[3];
    }
}

// ------- stage-2 finalize -----------------------------------------------------
__global__ __launch_bounds__(256) void finalize_kernel(
    const float* __restrict__ pkv, const float* __restrict__ pks,
    const float* __restrict__ psq, const float* __restrict__ psk,
    float* __restrict__ kvsum, float* __restrict__ kssum, float* __restrict__ scal)
{
    const int c = threadIdx.x;
    float kv = 0.f, ks = 0.f;
    #pragma unroll 4
    for (int b = 0; b < RBLOCKS; ++b) {
        kv += pkv[(size_t)b * HID + c];
        ks += pks[(size_t)b * HID + c];
    }
    kvsum[c] = kv;
    kssum[c] = ks;
    float sq = 0.f, sk = 0.f;
    for (int b = c; b < RBLOCKS; b += 256) { sq += psq[b]; sk += psk[b]; }
    #pragma unroll
    for (int off = 32; off > 0; off >>= 1) {
        sq += __shfl_down(sq, off, 64);
        sk += __shfl_down(sk, off, 64);
    }
    __shared__ float s1[4], s2[4];
    if ((c & 63) == 0) { s1[c >> 6] = sq; s2[c >> 6] = sk; }
    __syncthreads();
    if (c == 0) {
        const float SQ = s1[0] + s1[1] + s1[2] + s1[3];
        const float SK = s2[0] + s2[1] + s2[2] + s2[3];
        scal[0] = rsqrtf(SQ * SK);
    }
}

// ------- attention elementwise on packed qkv (in-place over q slice) ----------
__global__ __launch_bounds__(256) void attn_kernel(
    unsigned short* __restrict__ qkv,
    const float* __restrict__ kvsum, const float* __restrict__ kssum,
    const float* __restrict__ scal)
{
    const int row  = blockIdx.x * 8 + (threadIdx.x >> 5);
    const int lane = threadIdx.x & 31;
    const int c = lane * 8;                      // 8 cols; head = lane>>2
    const size_t base = (size_t)row * QKVM;
    const float inv = scal[0];
    const u16x8 q8 = *(const u16x8*)(qkv + base + c);
    const u16x8 v8 = *(const u16x8*)(qkv + base + 512 + c);
    float qf[8];
    float dot = 0.f;
    #pragma unroll
    for (int j = 0; j < 8; ++j) {
        qf[j] = bf2f(q8[j]);
        dot = fmaf(qf[j], kssum[c + j], dot);
    }
    dot += __shfl_xor(dot, 1, 4);
    dot += __shfl_xor(dot, 2, 4);
    const float rden = 1.0f / fmaf(dot, inv, (float)N_TOK);
    u16x8 o;
    #pragma unroll
    for (int j = 0; j < 8; ++j) {
        const float num = fmaf(qf[j] * kvsum[c + j], inv, bf2f(v8[j]) * (float)N_TOK);
        o[j] = f2bf(num * rden);
    }
    *(u16x8*)(qkv + base + c) = o;
}

extern "C" void kernel_launch(void* const* d_in, const int* in_sizes, int n_in,
                              void* d_out, int out_size, void* d_ws, size_t ws_size,
                              hipStream_t stream) {
    const float* x    = (const float*)d_in[0];
    const float* Wq   = (const float*)d_in[1];
    const float* bq   = (const float*)d_in[2];
    const float* Wk   = (const float*)d_in[3];
    const float* bk   = (const float*)d_in[4];
    const float* Wv   = (const float*)d_in[5];
    const float* bv   = (const float*)d_in[6];
    const float* Wh   = (const float*)d_in[7];
    const float* bh   = (const float*)d_in[8];
    const float* g1kv = (const float*)d_in[9];
    const float* b1kv = (const float*)d_in[10];
    const float* g1q  = (const float*)d_in[11];
    const float* b1q  = (const float*)d_in[12];
    const float* Wf1  = (const float*)d_in[13];
    const float* bf1  = (const float*)d_in[14];
    const float* Wf2  = (const float*)d_in[15];
    const float* bf2  = (const float*)d_in[16];
    const float* g2   = (const float*)d_in[17];
    const float* b2   = (const float*)d_in[18];
    float* out = (float*)d_out;

    // ---- workspace (~229.5 MiB; limit 256 MiB) ----
    // act (128MiB) overlays [nb1 32MiB | qkv 96MiB] (both dead by FFN1).
    char* p = (char*)d_ws;
    const size_t nh = (size_t)N_TOK * HID;
    unsigned short* nb1 = (unsigned short*)p;                   // 32 MiB
    unsigned short* qkv = (unsigned short*)(p + nh * 2);        // 96 MiB
    unsigned short* act = (unsigned short*)p;                   // 128 MiB overlay
    p += nh * 8;
    float* hpre = (float*)p; p += nh * 4;                       // 64 MiB
    unsigned short* nb2 = (unsigned short*)p; p += nh * 2;      // 32 MiB
    unsigned short* wtqkv = (unsigned short*)p; p += (size_t)3 * QKVM * HID * 2;
    unsigned short* wth   = (unsigned short*)p; p += (size_t)3 * HID * HID * 2;
    unsigned short* wtf1  = (unsigned short*)p; p += (size_t)3 * FFDIM * HID * 2;
    unsigned short* wtf2  = (unsigned short*)p; p += (size_t)3 * HID * FFDIM * 2;
    float* bqkv  = (float*)p; p += (size_t)3 * QKVM * sizeof(float);
    float* bf1f  = (float*)p; p += (size_t)3 * FFDIM * sizeof(float);
    float* pkv   = (float*)p; p += (size_t)RBLOCKS * HID * sizeof(float);
    float* pks   = (float*)p; p += (size_t)RBLOCKS * HID * sizeof(float);
    float* psq   = (float*)p; p += RBLOCKS * sizeof(float);
    float* psk   = (float*)p; p += RBLOCKS * sizeof(float);
    float* kvs   = (float*)p; p += HID * sizeof(float);
    float* kss   = (float*)p; p += HID * sizeof(float);
    float* scal  = (float*)p; p += 256;

    // ---- weight prep: LN-affine folded, transposed, bf16 ----
    const size_t qkvLS = (size_t)QKVM * HID;
    wconv<<<dim3(8, 8, 3),  256, 0, stream>>>(Wq,  g1q,  wtqkv, HID, HID, qkvLS, 0);
    wconv<<<dim3(8, 8, 3),  256, 0, stream>>>(Wk,  g1kv, wtqkv, HID, HID, qkvLS, 256);
    wconv<<<dim3(8, 8, 3),  256, 0, stream>>>(Wv,  g1kv, wtqkv, HID, HID, qkvLS, 512);
    wconv<<<dim3(8, 8, 3),  256, 0, stream>>>(Wh,  nullptr, wth, HID, HID, (size_t)HID * HID, 0);
    wconv<<<dim3(8, 32, 3), 256, 0, stream>>>(Wf1, g2,   wtf1, HID, FFDIM, (size_t)FFDIM * HID, 0);
    wconv<<<dim3(32, 8, 3), 256, 0, stream>>>(Wf2, nullptr, wtf2, FFDIM, HID, (size_t)HID * FFDIM, 0);
    biasfold<<<dim3(1, 3), 256, 0, stream>>>(Wq,  bq,  b1q,  bqkv, HID, HID, QKVM, 0);
    biasfold<<<dim3(1, 3), 256, 0, stream>>>(Wk,  bk,  b1kv, bqkv, HID, HID, QKVM, 256);
    biasfold<<<dim3(1, 3), 256, 0, stream>>>(Wv,  bv,  b1kv, bqkv, HID, HID, QKVM, 512);
    biasfold<<<dim3(4, 3), 256, 0, stream>>>(Wf1, bf1, b2,   bf1f, HID, FFDIM, FFDIM, 0);

    const dim3 gQKV(QKVM / 128, N_TOK / 128);   // (6, 512)
    const dim3 gH(HID / 128, N_TOK / 128);      // (2, 512)
    const dim3 gF1(FFDIM / 128, N_TOK / 128);   // (8, 512)

    for (int l = 0; l < 3; ++l) {
        const float* hin = (l == 0) ? x : out;
        const size_t vOff = (size_t)l * HID;

        ln_norm<<<N_TOK / 4, 256, 0, stream>>>(hin, nb1);
        mfma_gemm<HID, false, false, true><<<gQKV, 256, 0, stream>>>(
            nb1, HID, wtqkv + l * qkvLS, bqkv + l * QKVM, nullptr, qkv, QKVM);
        reduce_kernel<<<RBLOCKS, 256, 0, stream>>>(qkv, pkv, pks, psq, psk);
        finalize_kernel<<<1, 256, 0, stream>>>(pkv, pks, psq, psk, kvs, kss, scal);
        attn_kernel<<<N_TOK / 8, 256, 0, stream>>>(qkv, kvs, kss, scal);
        mfma_gemm<HID, false, true, false><<<gH, 256, 0, stream>>>(
            qkv, QKVM, wth + l * HID * HID, bh + vOff, hin, hpre, HID);
        ln_norm<<<N_TOK / 4, 256, 0, stream>>>(hpre, nb2);
        mfma_gemm<HID, true, false, true><<<gF1, 256, 0, stream>>>(
            nb2, HID, wtf1 + l * FFDIM * HID, bf1f + l * FFDIM, nullptr, act, FFDIM);
        mfma_gemm<FFDIM, false, true, false><<<gH, 256, 0, stream>>>(
            act, FFDIM, wtf2 + l * HID * FFDIM, bf2 + vOff, hpre, out, HID);
    }
}

// Round 7
// 1225.501 us; speedup vs baseline: 1.1274x; 1.1274x over previous
//
#include <hip/hip_runtime.h>
#include <math.h>

#define N_TOK 65536
#define HID   256
#define FFDIM 1024
#define QKVM  768
#define EPS_LN 1e-5f
#define RBLOCKS 256

typedef __bf16 bf16x8 __attribute__((ext_vector_type(8)));
typedef float  f32x4  __attribute__((ext_vector_type(4)));
typedef unsigned short u16x8 __attribute__((ext_vector_type(8)));

__device__ __forceinline__ float gelu_f(float x) {
    return 0.5f * x * (1.0f + erff(x * 0.70710678118654752f));
}
__device__ __forceinline__ float bf2f(unsigned short u) {
    return __uint_as_float(((unsigned int)u) << 16);
}
__device__ __forceinline__ unsigned short f2bf(float f) {
    unsigned int x = __float_as_uint(f);
    unsigned int r = ((x >> 16) & 1u) + 0x7fffu;
    return (unsigned short)((x + r) >> 16);
}
__device__ __forceinline__ void gload16(const void* g, void* l) {
    __builtin_amdgcn_global_load_lds(
        (const __attribute__((address_space(1))) void*)g,
        (__attribute__((address_space(3))) void*)l, 16, 0, 0);
}

// ------- weight fp32 [L,K,M] -> bf16 transposed [L][moff+M][K], row-scaled by g
__global__ __launch_bounds__(256) void wconv(
    const float* __restrict__ src, const float* __restrict__ g,
    unsigned short* __restrict__ dst,
    const int K, const int M, const size_t dstLS, const int moff)
{
    const int l = blockIdx.z;
    __shared__ float t[32][33];
    const int r  = threadIdx.x >> 3;
    const int c0 = (threadIdx.x & 7) * 4;
    const int bk = blockIdx.x * 32;
    const int bm = blockIdx.y * 32;
    float4 v4 = *(const float4*)(src + (size_t)l * K * M + (size_t)(bk + r) * M + bm + c0);
    if (g) {
        const float gv = g[(size_t)l * K + bk + r];
        v4.x *= gv; v4.y *= gv; v4.z *= gv; v4.w *= gv;
    }
    t[r][c0] = v4.x; t[r][c0+1] = v4.y; t[r][c0+2] = v4.z; t[r][c0+3] = v4.w;
    __syncthreads();
    ushort4 o;
    o.x = f2bf(t[c0+0][r]);
    o.y = f2bf(t[c0+1][r]);
    o.z = f2bf(t[c0+2][r]);
    o.w = f2bf(t[c0+3][r]);
    *(ushort4*)(dst + (size_t)l * dstLS + (size_t)(moff + bm + r) * K + bk + c0) = o;
}

// ------- bias fold: outb[l][moff+m] = bias[l][m] + sum_k bvec[l][k]*W[l][k][m]
__global__ __launch_bounds__(256) void biasfold(
    const float* __restrict__ W, const float* __restrict__ bias,
    const float* __restrict__ bvec, float* __restrict__ outb,
    const int K, const int M, const size_t outLS, const int moff)
{
    const int l = blockIdx.y;
    const int m = blockIdx.x * 256 + threadIdx.x;
    float acc = bias[(size_t)l * M + m];
    const float* Wl = W + (size_t)l * K * M;
    const float* bv = bvec + (size_t)l * K;
    for (int k = 0; k < K; ++k) acc = fmaf(bv[k], Wl[(size_t)k * M + m], acc);
    outb[(size_t)l * outLS + moff + m] = acc;
}

// ------- colsum of folded bf16 weight [L][M][256] -> S[L][M] ------------------
__global__ __launch_bounds__(256) void colsum(
    const unsigned short* __restrict__ wt, float* __restrict__ S, const int M)
{
    const int l = blockIdx.y;
    const int j = blockIdx.x * 256 + threadIdx.x;
    const unsigned short* rowp = wt + (size_t)l * M * HID + (size_t)j * HID;
    float s = 0.f;
    for (int k = 0; k < HID; k += 8) {
        const u16x8 u = *(const u16x8*)(rowp + k);
        #pragma unroll
        for (int t = 0; t < 8; ++t) s += bf2f(u[t]);
    }
    S[(size_t)l * M + j] = s;
}

// ------- fp32 -> bf16 cast ----------------------------------------------------
__global__ __launch_bounds__(256) void cast_bf(
    const float* __restrict__ x, unsigned short* __restrict__ hb)
{
    const size_t i = ((size_t)blockIdx.x * 256 + threadIdx.x) * 8;
    const float4 a = *(const float4*)(x + i);
    const float4 b = *(const float4*)(x + i + 4);
    u16x8 o;
    o[0] = f2bf(a.x); o[1] = f2bf(a.y); o[2] = f2bf(a.z); o[3] = f2bf(a.w);
    o[4] = f2bf(b.x); o[5] = f2bf(b.y); o[6] = f2bf(b.z); o[7] = f2bf(b.w);
    *(u16x8*)(hb + i) = o;
}

// ------- per-row mean/rstd of bf16 [N][256] -----------------------------------
__global__ __launch_bounds__(256) void stats_bf(
    const unsigned short* __restrict__ hb,
    float* __restrict__ mean, float* __restrict__ rstd)
{
    const int row  = blockIdx.x * 4 + (threadIdx.x >> 6);
    const int lane = threadIdx.x & 63;
    const ushort4 u = *(const ushort4*)(hb + (size_t)row * HID + lane * 4);
    const float x0 = bf2f(u.x), x1 = bf2f(u.y), x2 = bf2f(u.z), x3 = bf2f(u.w);
    float s  = x0 + x1 + x2 + x3;
    float s2 = fmaf(x0, x0, fmaf(x1, x1, fmaf(x2, x2, x3 * x3)));
    #pragma unroll
    for (int off = 32; off > 0; off >>= 1) {
        s  += __shfl_xor(s, off, 64);
        s2 += __shfl_xor(s2, off, 64);
    }
    if (lane == 0) {
        const float m   = s * (1.0f / HID);
        const float var = fmaxf(s2 * (1.0f / HID) - m * m, 0.f);
        mean[row] = m;
        rstd[row] = rsqrtf(var + EPS_LN);
    }
}

// ------- B-persistent bf16 MFMA GEMM (K=256): C = [LN](A) @ Wt^T + B ----------
// B-panel (128 cols x 256 K, 64KB) staged once into LDS; block loops over R
// row-tiles streaming A via global_load_lds (dbuf 16KB). Epilogue-LN:
// v = (acc - m[row]*S[col])*rs[row] + Bias[col].
template<int R, bool LNEP, bool GELU_EP, bool RES>
__global__ __launch_bounds__(256, 2) void gemm_bres(
    const unsigned short* __restrict__ A, const int lda,
    const unsigned short* __restrict__ Wt,
    const float* __restrict__ Bias, const float* __restrict__ S,
    const float* __restrict__ mean, const float* __restrict__ rstd,
    const unsigned short* __restrict__ res,
    unsigned short* __restrict__ C, const int ldc,
    const int nRowG, const int nBlkDiv8)
{
    __shared__ __align__(16) unsigned short Bp[8][128 * 32];  // 64 KB
    __shared__ __align__(16) unsigned short Ad[2][128 * 32];  // 16 KB
    const int tid = threadIdx.x;
    const int lane = tid & 63;
    const int wv   = tid >> 6;
    // XCD-bijective remap: consecutive cid -> same XCD; col-tile major.
    const int orig = blockIdx.x;
    const int cid  = (orig & 7) * nBlkDiv8 + (orig >> 3);
    const int ct   = cid / nRowG;
    const int rg   = cid - ct * nRowG;
    const int bn   = ct << 7;
    const int bm0  = rg * (R << 7);

    const int sr0  = (wv << 5) + (lane >> 2);
    const int schk = (lane & 3) ^ ((lane >> 2) & 3);
    // ---- B prologue: all 8 k-chunks, 128 rows ----
    {
        const unsigned short* bsrc = Wt + (size_t)(bn + sr0) * HID + schk * 8;
        char* bdst = (char*)&Bp[0][0] + (wv << 11);
        #pragma unroll
        for (int c = 0; c < 8; ++c)
            #pragma unroll
            for (int i = 0; i < 2; ++i)
                gload16(bsrc + (size_t)(i * 16) * HID + c * 32,
                        bdst + c * 8192 + (i << 10));
    }
    const unsigned short* asrc = A + (size_t)(bm0 + sr0) * lda + schk * 8;
    auto stageA = [&](int it) {
        const int rt = it >> 3, kc = it & 7, sl = it & 1;
        char* ad = (char*)&Ad[sl][0] + (wv << 11);
        const unsigned short* s0 = asrc + (size_t)(rt << 7) * lda + kc * 32;
        gload16(s0, ad);
        gload16(s0 + (size_t)16 * lda, ad + 1024);
    };
    stageA(0);

    const int lrow = lane & 15;
    const int kgrp = lane >> 4;
    const int wr = (wv >> 1) << 6;
    const int wc = (wv & 1) << 6;
    const int pa = (kgrp ^ (lrow & 3)) << 4;

    f32x4 acc[4][4];
    #pragma unroll
    for (int i = 0; i < 4; ++i)
        #pragma unroll
        for (int j = 0; j < 4; ++j)
            acc[i][j] = (f32x4){0.f, 0.f, 0.f, 0.f};

    __syncthreads();
    const int NIT = R * 8;
    #pragma unroll 8
    for (int it = 0; it < NIT; ++it) {
        const int kc = it & 7, sl = it & 1, rt = it >> 3;
        if (it + 1 < NIT) stageA(it + 1);
        const char* Ab = (const char*)&Ad[sl][0];
        const char* Bb = (const char*)&Bp[kc][0];
        bf16x8 af[4], bf[4];
        #pragma unroll
        for (int mi = 0; mi < 4; ++mi)
            af[mi] = *(const bf16x8*)(Ab + ((wr + mi * 16 + lrow) << 6) + pa);
        #pragma unroll
        for (int ni = 0; ni < 4; ++ni)
            bf[ni] = *(const bf16x8*)(Bb + ((wc + ni * 16 + lrow) << 6) + pa);
        #pragma unroll
        for (int mi = 0; mi < 4; ++mi)
            #pragma unroll
            for (int ni = 0; ni < 4; ++ni)
                acc[mi][ni] = __builtin_amdgcn_mfma_f32_16x16x32_bf16(
                    af[mi], bf[ni], acc[mi][ni], 0, 0, 0);
        if (kc == 7) {
            // epilogue for row-tile rt
            const int rowb = bm0 + (rt << 7) + wr;
            float bcol[4], scol[4];
            #pragma unroll
            for (int ni = 0; ni < 4; ++ni) {
                const int col = bn + wc + ni * 16 + lrow;
                bcol[ni] = Bias[col];
                if (LNEP) scol[ni] = S[col];
            }
            #pragma unroll
            for (int mi = 0; mi < 4; ++mi) {
                #pragma unroll
                for (int r = 0; r < 4; ++r) {
                    const int row = rowb + mi * 16 + kgrp * 4 + r;
                    float mrow = 0.f, rsrow = 0.f;
                    if (LNEP) { mrow = mean[row]; rsrow = rstd[row]; }
                    const size_t rb = (size_t)row * ldc;
                    #pragma unroll
                    for (int ni = 0; ni < 4; ++ni) {
                        const int col = bn + wc + ni * 16 + lrow;
                        float v = acc[mi][ni][r];
                        if (LNEP) v = (v - mrow * scol[ni]) * rsrow + bcol[ni];
                        else      v += bcol[ni];
                        if (RES)  v += bf2f(res[rb + col]);
                        if (GELU_EP) v = gelu_f(v);
                        C[rb + col] = f2bf(v);
                    }
                }
            }
            #pragma unroll
            for (int mi = 0; mi < 4; ++mi)
                #pragma unroll
                for (int ni = 0; ni < 4; ++ni)
                    acc[mi][ni] = (f32x4){0.f, 0.f, 0.f, 0.f};
        }
        __syncthreads();
    }
}

// ------- FFN2 GEMM (K=1024, M=256): std dbuf BK=32 + bf16 res, out bf16/fp32 --
template<bool OUTF32>
__global__ __launch_bounds__(256, 4) void gemm_ffn2(
    const unsigned short* __restrict__ A,
    const unsigned short* __restrict__ Wt,
    const float* __restrict__ Bias,
    const unsigned short* __restrict__ res,
    void* __restrict__ C)
{
    constexpr int K = FFDIM, M = HID, KT = K / 32;
    __shared__ __align__(16) unsigned short Abuf[2][128 * 32];
    __shared__ __align__(16) unsigned short Bbuf[2][128 * 32];
    const int tid  = threadIdx.x;
    const int lane = tid & 63;
    const int wv   = tid >> 6;
    const int orig = blockIdx.x;                 // 1024 blocks
    const int cid  = (orig & 7) * 128 + (orig >> 3);
    const int bn = (cid & 1) << 7;
    const int bm = (cid >> 1) << 7;
    const int sr0  = (wv << 5) + (lane >> 2);
    const int schk = (lane & 3) ^ ((lane >> 2) & 3);
    const unsigned short* Asrc = A  + (size_t)(bm + sr0) * K + schk * 8;
    const unsigned short* Bsrc = Wt + (size_t)(bn + sr0) * K + schk * 8;

    const int lrow = lane & 15;
    const int kgrp = lane >> 4;
    const int wr = (wv >> 1) << 6;
    const int wc = (wv & 1) << 6;

    f32x4 acc[4][4];
    #pragma unroll
    for (int i = 0; i < 4; ++i)
        #pragma unroll
        for (int j = 0; j < 4; ++j)
            acc[i][j] = (f32x4){0.f, 0.f, 0.f, 0.f};

    auto STAGE = [&](int b, int kt) {
        const int koff = kt * 32;
        char* ad = (char*)&Abuf[b][0] + (wv << 11);
        char* bd = (char*)&Bbuf[b][0] + (wv << 11);
        #pragma unroll
        for (int i = 0; i < 2; ++i) {
            gload16(Asrc + (size_t)(i * 16) * K + koff, ad + (i << 10));
            gload16(Bsrc + (size_t)(i * 16) * K + koff, bd + (i << 10));
        }
    };

    STAGE(0, 0);
    __syncthreads();
    const int pa = (kgrp ^ (lrow & 3)) << 4;
    for (int kt = 0; kt < KT; ++kt) {
        const int cur = kt & 1;
        if (kt + 1 < KT) STAGE(cur ^ 1, kt + 1);
        const char* Ab = (const char*)&Abuf[cur][0];
        const char* Bb = (const char*)&Bbuf[cur][0];
        bf16x8 af[4], bfr[4];
        #pragma unroll
        for (int mi = 0; mi < 4; ++mi)
            af[mi] = *(const bf16x8*)(Ab + ((wr + mi * 16 + lrow) << 6) + pa);
        #pragma unroll
        for (int ni = 0; ni < 4; ++ni)
            bfr[ni] = *(const bf16x8*)(Bb + ((wc + ni * 16 + lrow) << 6) + pa);
        #pragma unroll
        for (int mi = 0; mi < 4; ++mi)
            #pragma unroll
            for (int ni = 0; ni < 4; ++ni)
                acc[mi][ni] = __builtin_amdgcn_mfma_f32_16x16x32_bf16(
                    af[mi], bfr[ni], acc[mi][ni], 0, 0, 0);
        __syncthreads();
    }
    #pragma unroll
    for (int mi = 0; mi < 4; ++mi) {
        #pragma unroll
        for (int ni = 0; ni < 4; ++ni) {
            const int col = bn + wc + ni * 16 + lrow;
            const float bv = Bias[col];
            #pragma unroll
            for (int r = 0; r < 4; ++r) {
                const int row = bm + wr + mi * 16 + kgrp * 4 + r;
                float v = acc[mi][ni][r] + bv + bf2f(res[(size_t)row * M + col]);
                if (OUTF32) ((float*)C)[(size_t)row * M + col] = v;
                else ((unsigned short*)C)[(size_t)row * M + col] = f2bf(v);
            }
        }
    }
}

// ------- stage-1 reduction over packed qkv [N][768] ---------------------------
__global__ __launch_bounds__(256) void reduce_kernel(
    const unsigned short* __restrict__ qkv,
    float* __restrict__ pkv, float* __restrict__ pks,
    float* __restrict__ psq, float* __restrict__ psk)
{
    const int b   = blockIdx.x;
    const int tid = threadIdx.x;
    const int cg  = tid & 31;
    const int ro  = tid >> 5;
    const int c   = cg * 8;
    const int r0  = b * (N_TOK / RBLOCKS);
    float kv[8] = {}, ks[8] = {};
    float sq = 0.f, sk = 0.f;
    #pragma unroll 4
    for (int i = 0; i < (N_TOK / RBLOCKS) / 8; ++i) {
        const size_t base = (size_t)(r0 + ro + i * 8) * QKVM;
        const u16x8 q8 = *(const u16x8*)(qkv + base + c);
        const u16x8 k8 = *(const u16x8*)(qkv + base + 256 + c);
        const u16x8 v8 = *(const u16x8*)(qkv + base + 512 + c);
        #pragma unroll
        for (int j = 0; j < 8; ++j) {
            const float qf = bf2f(q8[j]), kf = bf2f(k8[j]), vf = bf2f(v8[j]);
            kv[j] = fmaf(kf, vf, kv[j]);
            ks[j] += kf;
            sq = fmaf(qf, qf, sq);
            sk = fmaf(kf, kf, sk);
        }
    }
    __shared__ float lkv[8][256];
    __shared__ float lks[8][256];
    #pragma unroll
    for (int j = 0; j < 8; ++j) { lkv[ro][c + j] = kv[j]; lks[ro][c + j] = ks[j]; }
    __syncthreads();
    float skv = 0.f, sks = 0.f;
    #pragma unroll
    for (int r = 0; r < 8; ++r) { skv += lkv[r][tid]; sks += lks[r][tid]; }
    pkv[(size_t)b * HID + tid] = skv;
    pks[(size_t)b * HID + tid] = sks;
    #pragma unroll
    for (int off = 32; off > 0; off >>= 1) {
        sq += __shfl_down(sq, off, 64);
        sk += __shfl_down(sk, off, 64);
    }
    __shared__ float s1[4], s2[4];
    if ((tid & 63) == 0) { s1[tid >> 6] = sq; s2[tid >> 6] = sk; }
    __syncthreads();
    if (tid == 0) {
        psq[b] = s1[0] + s1[1] + s1[2] + s1[3];
        psk[b] = s2[0] + s2[1] + s2[2] + s2[3];
    }
}

// ------- stage-2 finalize -----------------------------------------------------
__global__ __launch_bounds__(256) void finalize_kernel(
    const float* __restrict__ pkv, const float* __restrict__ pks,
    const float* __restrict__ psq, const float* __restrict__ psk,
    float* __restrict__ kvsum, float* __restrict__ kssum, float* __restrict__ scal)
{
    const int c = threadIdx.x;
    float kv = 0.f, ks = 0.f;
    #pragma unroll 4
    for (int b = 0; b < RBLOCKS; ++b) {
        kv += pkv[(size_t)b * HID + c];
        ks += pks[(size_t)b * HID + c];
    }
    kvsum[c] = kv;
    kssum[c] = ks;
    float sq = 0.f, sk = 0.f;
    for (int b = c; b < RBLOCKS; b += 256) { sq += psq[b]; sk += psk[b]; }
    #pragma unroll
    for (int off = 32; off > 0; off >>= 1) {
        sq += __shfl_down(sq, off, 64);
        sk += __shfl_down(sk, off, 64);
    }
    __shared__ float s1[4], s2[4];
    if ((c & 63) == 0) { s1[c >> 6] = sq; s2[c >> 6] = sk; }
    __syncthreads();
    if (c == 0) {
        const float SQ = s1[0] + s1[1] + s1[2] + s1[3];
        const float SK = s2[0] + s2[1] + s2[2] + s2[3];
        scal[0] = rsqrtf(SQ * SK);
    }
}

// ------- attention elementwise on packed qkv (in-place over q slice) ----------
__global__ __launch_bounds__(256) void attn_kernel(
    unsigned short* __restrict__ qkv,
    const float* __restrict__ kvsum, const float* __restrict__ kssum,
    const float* __restrict__ scal)
{
    const int row  = blockIdx.x * 8 + (threadIdx.x >> 5);
    const int lane = threadIdx.x & 31;
    const int c = lane * 8;
    const size_t base = (size_t)row * QKVM;
    const float inv = scal[0];
    const u16x8 q8 = *(const u16x8*)(qkv + base + c);
    const u16x8 v8 = *(const u16x8*)(qkv + base + 512 + c);
    float qf[8];
    float dot = 0.f;
    #pragma unroll
    for (int j = 0; j < 8; ++j) {
        qf[j] = bf2f(q8[j]);
        dot = fmaf(qf[j], kssum[c + j], dot);
    }
    dot += __shfl_xor(dot, 1, 4);
    dot += __shfl_xor(dot, 2, 4);
    const float rden = 1.0f / fmaf(dot, inv, (float)N_TOK);
    u16x8 o;
    #pragma unroll
    for (int j = 0; j < 8; ++j) {
        const float num = fmaf(qf[j] * kvsum[c + j], inv, bf2f(v8[j]) * (float)N_TOK);
        o[j] = f2bf(num * rden);
    }
    *(u16x8*)(qkv + base + c) = o;
}

extern "C" void kernel_launch(void* const* d_in, const int* in_sizes, int n_in,
                              void* d_out, int out_size, void* d_ws, size_t ws_size,
                              hipStream_t stream) {
    const float* x    = (const float*)d_in[0];
    const float* Wq   = (const float*)d_in[1];
    const float* bq   = (const float*)d_in[2];
    const float* Wk   = (const float*)d_in[3];
    const float* bk   = (const float*)d_in[4];
    const float* Wv   = (const float*)d_in[5];
    const float* bv   = (const float*)d_in[6];
    const float* Wh   = (const float*)d_in[7];
    const float* bh   = (const float*)d_in[8];
    const float* g1kv = (const float*)d_in[9];
    const float* b1kv = (const float*)d_in[10];
    const float* g1q  = (const float*)d_in[11];
    const float* b1q  = (const float*)d_in[12];
    const float* Wf1  = (const float*)d_in[13];
    const float* bf1  = (const float*)d_in[14];
    const float* Wf2  = (const float*)d_in[15];
    const float* bf2  = (const float*)d_in[16];
    const float* g2   = (const float*)d_in[17];
    const float* b2   = (const float*)d_in[18];
    float* out = (float*)d_out;

    // ---- workspace (~200 MiB; limit ~256 MiB) ----
    // act (128 MiB) region: qkv (96 MiB) overlays its start (dead before FFN1).
    char* p = (char*)d_ws;
    const size_t nh = (size_t)N_TOK * HID;
    unsigned short* hb   = (unsigned short*)p; p += nh * 2;       // 32 MiB (residual)
    unsigned short* hpre = (unsigned short*)p; p += nh * 2;       // 32 MiB
    unsigned short* act  = (unsigned short*)p;                    // 128 MiB
    unsigned short* qkv  = act;                                   // overlay (96 MiB)
    p += nh * 8;
    float* meanb = (float*)p; p += N_TOK * sizeof(float);
    float* rstdb = (float*)p; p += N_TOK * sizeof(float);
    unsigned short* wtqkv = (unsigned short*)p; p += (size_t)3 * QKVM * HID * 2;
    unsigned short* wth   = (unsigned short*)p; p += (size_t)3 * HID * HID * 2;
    unsigned short* wtf1  = (unsigned short*)p; p += (size_t)3 * FFDIM * HID * 2;
    unsigned short* wtf2  = (unsigned short*)p; p += (size_t)3 * HID * FFDIM * 2;
    float* bqkv = (float*)p; p += (size_t)3 * QKVM * sizeof(float);
    float* bf1f = (float*)p; p += (size_t)3 * FFDIM * sizeof(float);
    float* Sqkv = (float*)p; p += (size_t)3 * QKVM * sizeof(float);
    float* Sf1  = (float*)p; p += (size_t)3 * FFDIM * sizeof(float);
    float* pkv  = (float*)p; p += (size_t)RBLOCKS * HID * sizeof(float);
    float* pks  = (float*)p; p += (size_t)RBLOCKS * HID * sizeof(float);
    float* psq  = (float*)p; p += RBLOCKS * sizeof(float);
    float* psk  = (float*)p; p += RBLOCKS * sizeof(float);
    float* kvs  = (float*)p; p += HID * sizeof(float);
    float* kss  = (float*)p; p += HID * sizeof(float);
    float* scal = (float*)p; p += 256;

    // ---- prep: fold LN-affine into weights, transpose, bf16; colsums; biases -
    const size_t qkvLS = (size_t)QKVM * HID;
    wconv<<<dim3(8, 8, 3),  256, 0, stream>>>(Wq,  g1q,  wtqkv, HID, HID, qkvLS, 0);
    wconv<<<dim3(8, 8, 3),  256, 0, stream>>>(Wk,  g1kv, wtqkv, HID, HID, qkvLS, 256);
    wconv<<<dim3(8, 8, 3),  256, 0, stream>>>(Wv,  g1kv, wtqkv, HID, HID, qkvLS, 512);
    wconv<<<dim3(8, 8, 3),  256, 0, stream>>>(Wh,  nullptr, wth, HID, HID, (size_t)HID * HID, 0);
    wconv<<<dim3(8, 32, 3), 256, 0, stream>>>(Wf1, g2,   wtf1, HID, FFDIM, (size_t)FFDIM * HID, 0);
    wconv<<<dim3(32, 8, 3), 256, 0, stream>>>(Wf2, nullptr, wtf2, FFDIM, HID, (size_t)HID * FFDIM, 0);
    colsum<<<dim3(3, 3), 256, 0, stream>>>(wtqkv, Sqkv, QKVM);
    colsum<<<dim3(4, 3), 256, 0, stream>>>(wtf1,  Sf1,  FFDIM);
    biasfold<<<dim3(1, 3), 256, 0, stream>>>(Wq,  bq,  b1q,  bqkv, HID, HID, QKVM, 0);
    biasfold<<<dim3(1, 3), 256, 0, stream>>>(Wk,  bk,  b1kv, bqkv, HID, HID, QKVM, 256);
    biasfold<<<dim3(1, 3), 256, 0, stream>>>(Wv,  bv,  b1kv, bqkv, HID, HID, QKVM, 512);
    biasfold<<<dim3(4, 3), 256, 0, stream>>>(Wf1, bf1, b2,   bf1f, HID, FFDIM, FFDIM, 0);
    cast_bf<<<nh / (256 * 8), 256, 0, stream>>>(x, hb);

    for (int l = 0; l < 3; ++l) {
        stats_bf<<<N_TOK / 4, 256, 0, stream>>>(hb, meanb, rstdb);
        // QKV: 6 col-tiles x 256 row-groups (R=2) = 1536 blocks
        gemm_bres<2, true, false, false><<<1536, 256, 0, stream>>>(
            hb, HID, wtqkv + l * qkvLS, bqkv + l * QKVM, Sqkv + l * QKVM,
            meanb, rstdb, nullptr, qkv, QKVM, 256, 192);
        reduce_kernel<<<RBLOCKS, 256, 0, stream>>>(qkv, pkv, pks, psq, psk);
        finalize_kernel<<<1, 256, 0, stream>>>(pkv, pks, psq, psk, kvs, kss, scal);
        attn_kernel<<<N_TOK / 8, 256, 0, stream>>>(qkv, kvs, kss, scal);
        // H: A = attn (q slice of qkv, lda 768), res = hb -> hpre
        gemm_bres<2, false, false, true><<<512, 256, 0, stream>>>(
            qkv, QKVM, wth + (size_t)l * HID * HID, bh + (size_t)l * HID, nullptr,
            nullptr, nullptr, hb, hpre, HID, 256, 64);
        stats_bf<<<N_TOK / 4, 256, 0, stream>>>(hpre, meanb, rstdb);
        // FFN1: epilogue-LN + GELU -> act
        gemm_bres<4, true, true, false><<<1024, 256, 0, stream>>>(
            hpre, HID, wtf1 + (size_t)l * FFDIM * HID, bf1f + (size_t)l * FFDIM,
            Sf1 + (size_t)l * FFDIM, meanb, rstdb, nullptr, act, FFDIM, 128, 128);
        // FFN2: + res(hpre) -> next hb (bf16) or final d_out (fp32)
        if (l < 2)
            gemm_ffn2<false><<<1024, 256, 0, stream>>>(
                act, wtf2 + (size_t)l * HID * FFDIM, bf2 + (size_t)l * HID, hpre, hb);
        else
            gemm_ffn2<true><<<1024, 256, 0, stream>>>(
                act, wtf2 + (size_t)l * HID * FFDIM, bf2 + (size_t)l * HID, hpre, out);
    }
}